// Round 12
// baseline (503.103 us; speedup 1.0000x reference)
//
#include <hip/hip_runtime.h>
#include <hip/hip_bf16.h>
#include <math.h>

// Problem constants
#define BB    2
#define CC    256
#define FF    16
#define NN    4096      // 64*64 spatial
#define FN    (FF*NN)   // 65536
#define BF    32        // BB*FF
#define HEADS 8
#define DH    32
#define HID   256
#define NS    8         // n-range splits in K1
#define TN1   64        // n tile width (K1)
#define TN3   64        // n tile width (K3)
#define SCALEF 0.17677669529663687f   // 32^-0.5

// ushort offsets within U (fragment-major):
// WQF  [w:8][rf:2][kc:8][g:4][m:16][i:8]           = 65536
// WKVF [w:8][cg:4][kc:8][g:4][m:16][i:8]           = 131072
// MF   [bf:32][w:8][rf:2][kc:8][g:4][m:16][i:8]    = BF*65536
#define WQHI_O  0
#define WQLO_O  65536
#define WKVHI_O 131072
#define WKVLO_O 262144
#define MHI_O   393216
#define MLO_O   (393216 + BF*256*256)
#define USH_ELEMS (393216 + 2*BF*256*256)   // 4,587,520 ushorts

typedef __attribute__((ext_vector_type(8))) short bf16x8;
typedef __attribute__((ext_vector_type(8))) unsigned short u16x8;
typedef __attribute__((ext_vector_type(4))) unsigned short u16x4;
typedef __attribute__((ext_vector_type(4))) float f32x4;

#define MFMA16(a, b, c) __builtin_amdgcn_mfma_f32_16x16x32_bf16((a), (b), (c), 0, 0, 0)

// Raw barrier: LDS-visibility only (lgkmcnt) — global loads stay in flight.
__device__ __forceinline__ void bar_lgkm() {
    asm volatile("s_waitcnt lgkmcnt(0)" ::: "memory");
    __builtin_amdgcn_s_barrier();
    asm volatile("" ::: "memory");
}

// HW bf16 convert (RNE).
__device__ inline unsigned short f2bf(float f) {
    union { __hip_bfloat16 h; unsigned short u; } cv;
    cv.h = __float2bfloat16(f);
    return cv.u;
}
__device__ inline float bf2f(unsigned short h) {
    return __uint_as_float(((unsigned int)h) << 16);
}

// K0: split w_qkv into bf16 hi/lo, FRAGMENT-MAJOR (lane l reads [l*8 .. l*8+8)).
__global__ __launch_bounds__(256) void k0_prep(const float* __restrict__ wqkv,
                                               unsigned short* __restrict__ wqfhi,
                                               unsigned short* __restrict__ wqflo,
                                               unsigned short* __restrict__ wkvfhi,
                                               unsigned short* __restrict__ wkvflo) {
    int idx = blockIdx.x * 256 + threadIdx.x;   // 0 .. 768*256
    int o = idx >> 8;
    int c = idx & 255;
    float v = wqkv[idx];
    unsigned short hv = f2bf(v);
    unsigned short lv = f2bf(v - bf2f(hv));
    int kc = c >> 5, g = (c >> 3) & 3, i = c & 7;
    if (o < 256) {
        int w = o >> 5, rf = (o >> 4) & 1, m = o & 15;
        int fi = w * 8192 + rf * 4096 + kc * 512 + g * 128 + m * 8 + i;
        wqfhi[fi] = hv;
        wqflo[fi] = lv;
    } else {
        int r = o - 256;
        int w = r >> 6, cg = (r >> 4) & 3, m = r & 15;
        int fi = w * 16384 + cg * 4096 + kc * 512 + g * 128 + m * 8 + i;
        wkvfhi[fi] = hv;
        wkvflo[fi] = lv;
    }
}

// K1 (MFMA, per-head waves): wave = head h. k-hi weight fragments cached in
// registers across the whole tile loop (loop-invariant; removes 16 of 64
// per-tile L2 loads and de-latencies the 2x-used operand).
__global__ __launch_bounds__(512, 2) void k1_mfma(const float* __restrict__ x,
                                                  const unsigned short* __restrict__ wkvfhi,
                                                  const unsigned short* __restrict__ wkvflo,
                                                  float* __restrict__ partC,
                                                  float* __restrict__ partz) {
    const int ns = blockIdx.x;      // 0..NS-1
    const int bf = blockIdx.y;
    const int b = bf >> 4, f = bf & 15;
    const float* xbase = x + (size_t)b * (CC * FN) + (size_t)f * NN;
    const int t = threadIdx.x;
    const int w = t >> 6;           // wave 0..7 = head h
    const int l = t & 63;
    const int g = l >> 4, m = l & 15;

    const int strip = NN / NS;      // 512
    const int ntiles = strip / TN1; // 8
    const int nbase = ns * strip;

    // LDS: XT 64 KiB (2 planes x 32 KiB) + wave-private PV 80 KiB (8 x 10 KiB)
    __shared__ __align__(16) char LDS[147456];
    char* X0 = LDS;                 // XT hi [64 n][256 c] bf16, swizzled (rows 512B)
    char* X1 = LDS + 32768;         // XT lo
    char* PV0 = LDS + 65536 + w * 10240;          // hi
    char* PV1 = LDS + 65536 + w * 10240 + 5120;   // lo

    f32x4 ctx[2][2];
#pragma unroll
    for (int df = 0; df < 2; ++df)
#pragma unroll
        for (int ef = 0; ef < 2; ++ef) ctx[df][ef] = (f32x4)0.f;
    float zacc[2] = {0.f, 0.f};

    // fragment-major weight bases: head h k-rows (32h..32h+32), v-rows (+256)
    const int kbase = (w >> 1) * 16384 + (w & 1) * 8192 + l * 8;
    const int vbase = (4 + (w >> 1)) * 16384 + (w & 1) * 8192 + l * 8;
    const unsigned short* bkh = wkvfhi + kbase;
    const unsigned short* bkl = wkvflo + kbase;
    const unsigned short* bvh = wkvfhi + vbase;
    const unsigned short* bvl = wkvflo + vbase;

    // ---- k-hi weight cache: loop-invariant, loaded once (static indices) ----
    bf16x8 wkh[16];   // [kc*2 + cg]
#pragma unroll
    for (int kc = 0; kc < 8; ++kc) {
        wkh[kc * 2 + 0] = *(const bf16x8*)(bkh + kc * 512);
        wkh[kc * 2 + 1] = *(const bf16x8*)(bkh + 4096 + kc * 512);
    }

    // staging geometry: lane owns column nl = l, 32 c's starting at w*32
    const int nl = l;
    const int c0 = w * 32;

    // ---- prologue: nt-load tile 0, stage it, nt-prefetch tile 1 ----
    float v[32];
#pragma unroll
    for (int i = 0; i < 32; ++i)
        v[i] = __builtin_nontemporal_load(&xbase[(size_t)(c0 + i) * FN + nbase + nl]);

#pragma unroll
    for (int qq = 0; qq < 4; ++qq) {
        u16x8 vh, vl;
#pragma unroll
        for (int i = 0; i < 8; ++i) {
            float fv = v[qq * 8 + i];
            unsigned short hv = f2bf(fv);
            vh[i] = hv;
            vl[i] = f2bf(fv - bf2f(hv));
        }
        int off = (nl * 512 + (c0 + qq * 8) * 2) ^ ((nl & 31) << 4);
        *(u16x8*)(X0 + off) = vh;
        *(u16x8*)(X1 + off) = vl;
    }
    if (ntiles > 1) {
#pragma unroll
        for (int i = 0; i < 32; ++i)
            v[i] = __builtin_nontemporal_load(&xbase[(size_t)(c0 + i) * FN + nbase + TN1 + nl]);
    }
    bar_lgkm();   // B1: XT(0) visible; prefetch(1) stays in flight

    for (int tile = 0; tile < ntiles; ++tile) {
        // ---- GEMM1: acc[rf][cg] = D[n=16rf+4g+r][head h kv], split-bf16 ----
        f32x4 acc[4][4];
#pragma unroll
        for (int rf = 0; rf < 4; ++rf)
#pragma unroll
            for (int cg = 0; cg < 4; ++cg) acc[rf][cg] = (f32x4)0.f;

#pragma unroll
        for (int kc = 0; kc < 8; ++kc) {
            bf16x8 ah[4], al[4];
#pragma unroll
            for (int rf = 0; rf < 4; ++rf) {
                int n = 16 * rf + m;
                int off = (n * 512 + (32 * kc + 8 * g) * 2) ^ ((n & 31) << 4);
                ah[rf] = *(const bf16x8*)(X0 + off);
                al[rf] = *(const bf16x8*)(X1 + off);
            }
            bf16x8 bh[4], bl[4];
            bh[0] = wkh[kc * 2 + 0];            // cached k-hi
            bh[1] = wkh[kc * 2 + 1];
            bl[0] = *(const bf16x8*)(bkl + kc * 512);
            bl[1] = *(const bf16x8*)(bkl + 4096 + kc * 512);
            bh[2] = *(const bf16x8*)(bvh + kc * 512);
            bl[2] = *(const bf16x8*)(bvl + kc * 512);
            bh[3] = *(const bf16x8*)(bvh + 4096 + kc * 512);
            bl[3] = *(const bf16x8*)(bvl + 4096 + kc * 512);
#pragma unroll
            for (int rf = 0; rf < 4; ++rf)
#pragma unroll
                for (int cg = 0; cg < 4; ++cg) {
                    acc[rf][cg] = MFMA16(ah[rf], bh[cg], acc[rf][cg]);
                    acc[rf][cg] = MFMA16(ah[rf], bl[cg], acc[rf][cg]);
                    acc[rf][cg] = MFMA16(al[rf], bh[cg], acc[rf][cg]);
                }
        }
        bar_lgkm();   // B2: all XT reads done -> XT region free for restage

        // ---- restage next tile's XT + nt-prefetch tile+2 (barrier-bounded) ----
        if (tile + 1 < ntiles) {
#pragma unroll
            for (int qq = 0; qq < 4; ++qq) {
                u16x8 vh, vl;
#pragma unroll
                for (int i = 0; i < 8; ++i) {
                    float fv = v[qq * 8 + i];
                    unsigned short hv = f2bf(fv);
                    vh[i] = hv;
                    vl[i] = f2bf(fv - bf2f(hv));
                }
                int off = (nl * 512 + (c0 + qq * 8) * 2) ^ ((nl & 31) << 4);
                *(u16x8*)(X0 + off) = vh;
                *(u16x8*)(X1 + off) = vl;
            }
            if (tile + 2 < ntiles) {
                int n0n = nbase + (tile + 2) * TN1;
#pragma unroll
                for (int i = 0; i < 32; ++i)
                    v[i] = __builtin_nontemporal_load(&xbase[(size_t)(c0 + i) * FN + n0n + nl]);
            }
            bar_lgkm();   // B1': next XT visible; waves free to drift below
        }

        // ---- exp + z on k-halves (cg 0,1), register-only ----
#pragma unroll
        for (int cg = 0; cg < 2; ++cg) {
            float s = 0.f;
#pragma unroll
            for (int rf = 0; rf < 4; ++rf)
#pragma unroll
                for (int r = 0; r < 4; ++r) {
                    float e = __expf(acc[rf][cg][r]);
                    acc[rf][cg][r] = e;
                    s += e;
                }
            s += __shfl_xor(s, 16);
            s += __shfl_xor(s, 32);
            zacc[cg] += s;
        }

        // ---- PV: wave-private, 2 n-chunks of 32, no barriers ----
#pragma unroll
        for (int ks = 0; ks < 2; ++ks) {
#pragma unroll
            for (int rfh = 0; rfh < 2; ++rfh) {
                int rf = 2 * ks + rfh;
#pragma unroll
                for (int cg = 0; cg < 4; ++cg) {
                    int row = 16 * cg + m;
                    u16x4 vh4, vl4;
#pragma unroll
                    for (int r = 0; r < 4; ++r) {
                        float fv = acc[rf][cg][r];
                        unsigned short hv = f2bf(fv);
                        vh4[r] = hv;
                        vl4[r] = f2bf(fv - bf2f(hv));
                    }
                    int off = row * 80 + 32 * rfh + 8 * g;
                    *(u16x4*)(PV0 + off) = vh4;
                    *(u16x4*)(PV1 + off) = vl4;
                }
            }
            bf16x8 ph[2], pl[2], vh_[2], vl_[2];
#pragma unroll
            for (int df = 0; df < 2; ++df) {
                int off = (16 * df + m) * 80 + 16 * g;
                ph[df] = *(const bf16x8*)(PV0 + off);
                pl[df] = *(const bf16x8*)(PV1 + off);
            }
#pragma unroll
            for (int ef = 0; ef < 2; ++ef) {
                int off = (32 + 16 * ef + m) * 80 + 16 * g;
                vh_[ef] = *(const bf16x8*)(PV0 + off);
                vl_[ef] = *(const bf16x8*)(PV1 + off);
            }
#pragma unroll
            for (int df = 0; df < 2; ++df)
#pragma unroll
                for (int ef = 0; ef < 2; ++ef) {
                    ctx[df][ef] = MFMA16(ph[df], vh_[ef], ctx[df][ef]);
                    ctx[df][ef] = MFMA16(ph[df], vl_[ef], ctx[df][ef]);
                    ctx[df][ef] = MFMA16(pl[df], vh_[ef], ctx[df][ef]);
                }
        }
    }

    // ---- write partials ----
    if (g == 0) {
#pragma unroll
        for (int cg = 0; cg < 2; ++cg)
            partz[(size_t)(bf * NS + ns) * 256 + 32 * w + 16 * cg + m] = zacc[cg];
    }
#pragma unroll
    for (int df = 0; df < 2; ++df)
#pragma unroll
        for (int ef = 0; ef < 2; ++ef)
#pragma unroll
            for (int r = 0; r < 4; ++r) {
                int row = 32 * w + 16 * df + 4 * g + r;
                int col = 16 * ef + m;
                partC[((size_t)(bf * NS + ns) * 256 + row) * 32 + col] = ctx[df][ef][r];
            }
}

// K2: per (bf, head): merge partials -> ctx (SCALE/z folded);
// M[o][32h+d] = sum_e wout[o][32h+e]*ctx[d][e], bf16 hi/lo FRAGMENT-MAJOR.
__global__ __launch_bounds__(256) void k2_M(const float* __restrict__ partC,
                                            const float* __restrict__ partz,
                                            const float* __restrict__ wout,
                                            unsigned short* __restrict__ Mhi,
                                            unsigned short* __restrict__ Mlo,
                                            int nsplit) {
    const int bf = blockIdx.x;
    const int h  = blockIdx.y;
    const int t  = threadIdx.x;

    __shared__ float ctxs[32][33];
    __shared__ float zs[32];

    if (t < 32) {
        float z = 0.f;
        for (int ns2 = 0; ns2 < nsplit; ++ns2)
            z += partz[(size_t)(bf * nsplit + ns2) * 256 + 32 * h + t];
        zs[t] = SCALEF / z;
    }
    {
        const int d = t & 31, eg = t >> 5;
        float4 c = make_float4(0.f, 0.f, 0.f, 0.f);
        for (int ns2 = 0; ns2 < nsplit; ++ns2) {
            const float4 p = *(const float4*)&partC[
                ((size_t)(bf * nsplit + ns2) * 256 + 32 * h + d) * 32 + 4 * eg];
            c.x += p.x; c.y += p.y; c.z += p.z; c.w += p.w;
        }
        __syncthreads();   // zs ready
        float zi = zs[d];
        ctxs[d][4 * eg + 0] = c.x * zi;
        ctxs[d][4 * eg + 1] = c.y * zi;
        ctxs[d][4 * eg + 2] = c.z * zi;
        ctxs[d][4 * eg + 3] = c.w * zi;
    }
    __syncthreads();

    const int o = t;
    float wo[32];
#pragma unroll
    for (int j = 0; j < 8; ++j) {
        float4 w4 = *(const float4*)&wout[o * 256 + 32 * h + 4 * j];
        wo[4 * j + 0] = w4.x;
        wo[4 * j + 1] = w4.y;
        wo[4 * j + 2] = w4.z;
        wo[4 * j + 3] = w4.w;
    }
    const int wq = o >> 5, rf = (o >> 4) & 1, mm = o & 15;
    const size_t fbase = (size_t)bf * 65536 + wq * 8192 + rf * 4096 + h * 512 + mm * 8;
#pragma unroll
    for (int d = 0; d < 32; ++d) {
        float mv = 0.f;
#pragma unroll
        for (int e = 0; e < 32; ++e) mv += wo[e] * ctxs[d][e];
        unsigned short hv = f2bf(mv);
        unsigned short lv = f2bf(mv - bf2f(hv));
        size_t fi = fbase + (size_t)(d >> 3) * 128 + (d & 7);
        Mhi[fi] = hv;
        Mlo[fi] = lv;
    }
}

// K3 (MFMA): per (bf, 64-col tile). M-hi(rf=0) prefetched at kernel start;
// raw lgkm barriers keep those loads in flight across the phase boundaries.
__global__ __launch_bounds__(512, 4) void k3_mfma(const float* __restrict__ x,
                                                  const unsigned short* __restrict__ wqfhi,
                                                  const unsigned short* __restrict__ wqflo,
                                                  const unsigned short* __restrict__ mfhi,
                                                  const unsigned short* __restrict__ mflo,
                                                  const float* __restrict__ bout,
                                                  float* __restrict__ out) {
    const int tile = blockIdx.x;    // 0..63
    const int bf = blockIdx.y;
    const int b = bf >> 4, f = bf & 15;
    const size_t xoff = (size_t)b * (CC * FN) + (size_t)f * NN;
    const float* xg = x + xoff;
    float* og = out + xoff;
    const int n0 = tile * TN3;
    const int t = threadIdx.x;
    const int w = t >> 6;           // wave 0..7 (= head for GEMM1)
    const int l = t & 63;
    const int g = l >> 4, m = l & 15;

    __shared__ unsigned short lds[2][64][256];
    char* L0 = (char*)&lds[0][0][0];
    char* L1 = (char*)&lds[1][0][0];

    const unsigned short* Mh = mfhi + (size_t)bf * 65536 + w * 8192 + l * 8;
    const unsigned short* Ml = mflo + (size_t)bf * 65536 + w * 8192 + l * 8;

    // ---- stage: transpose X[c][n] -> XT[n][c] bf16 hi/lo, swizzled (nt loads) ----
#pragma unroll
    for (int q = 0; q < 4; ++q) {
        int c0 = 32 * w + 8 * q;
        float v[8];
#pragma unroll
        for (int i = 0; i < 8; ++i)
            v[i] = __builtin_nontemporal_load(&xg[(size_t)(c0 + i) * FN + n0 + l]);
        u16x8 vh, vl;
#pragma unroll
        for (int i = 0; i < 8; ++i) {
            unsigned short hv = f2bf(v[i]);
            vh[i] = hv;
            vl[i] = f2bf(v[i] - bf2f(hv));
        }
        int off = (l * 512 + c0 * 2) ^ ((l & 31) << 4);
        *(u16x8*)(L0 + off) = vh;
        *(u16x8*)(L1 + off) = vl;
    }

    // ---- prefetch GEMM2's M-hi rf=0 fragments (in flight across barriers) ----
    bf16x8 mh0[8];
#pragma unroll
    for (int kc = 0; kc < 8; ++kc) mh0[kc] = *(const bf16x8*)(Mh + kc * 512);

    bar_lgkm();

    // fragment-major A bases
    const unsigned short* aqh = wqfhi + w * 8192 + l * 8;
    const unsigned short* aql = wqflo + w * 8192 + l * 8;

    // ---- GEMM1: qacc[rf][cg] = Q[32w+16rf+4g+r][n0+16cg+m], split-bf16 ----
    f32x4 qacc[2][4];
#pragma unroll
    for (int rf = 0; rf < 2; ++rf)
#pragma unroll
        for (int cg = 0; cg < 4; ++cg) qacc[rf][cg] = (f32x4)0.f;

#pragma unroll
    for (int kc = 0; kc < 8; ++kc) {
        bf16x8 ah[2], al[2];
#pragma unroll
        for (int rf = 0; rf < 2; ++rf) {
            ah[rf] = *(const bf16x8*)(aqh + rf * 4096 + kc * 512);
            al[rf] = *(const bf16x8*)(aql + rf * 4096 + kc * 512);
        }
        bf16x8 bh[4], bl[4];
#pragma unroll
        for (int cg = 0; cg < 4; ++cg) {
            int n = 16 * cg + m;
            int off = (n * 512 + (32 * kc + 8 * g) * 2) ^ ((n & 31) << 4);
            bh[cg] = *(const bf16x8*)(L0 + off);
            bl[cg] = *(const bf16x8*)(L1 + off);
        }
#pragma unroll
        for (int rf = 0; rf < 2; ++rf)
#pragma unroll
            for (int cg = 0; cg < 4; ++cg) {
                qacc[rf][cg] = MFMA16(ah[rf], bh[cg], qacc[rf][cg]);
                qacc[rf][cg] = MFMA16(ah[rf], bl[cg], qacc[rf][cg]);
                qacc[rf][cg] = MFMA16(al[rf], bh[cg], qacc[rf][cg]);
            }
    }

    // ---- softmax over d (in-register; head = w) ----
    float zinv[4];
#pragma unroll
    for (int cg = 0; cg < 4; ++cg) {
        float s = 0.f;
#pragma unroll
        for (int rf = 0; rf < 2; ++rf)
#pragma unroll
            for (int r = 0; r < 4; ++r) {
                float e = __expf(qacc[rf][cg][r]);
                qacc[rf][cg][r] = e;
                s += e;
            }
        s += __shfl_xor(s, 16);
        s += __shfl_xor(s, 32);
        zinv[cg] = 1.f / s;   // SCALE folded into M
    }

    bar_lgkm();

    // ---- write QsmT[n][hd] bf16 hi/lo (aliased over XT planes) ----
#pragma unroll
    for (int rf = 0; rf < 2; ++rf)
#pragma unroll
        for (int cg = 0; cg < 4; ++cg) {
            int n = 16 * cg + m;
            int hd0 = 32 * w + 16 * rf + 4 * g;
            u16x4 vh, vl;
#pragma unroll
            for (int r = 0; r < 4; ++r) {
                float qv = qacc[rf][cg][r] * zinv[cg];
                unsigned short hv = f2bf(qv);
                vh[r] = hv;
                vl[r] = f2bf(qv - bf2f(hv));
            }
            int off = (n * 512 + hd0 * 2) ^ ((n & 31) << 4);
            *(u16x4*)(L0 + off) = vh;
            *(u16x4*)(L1 + off) = vl;
        }
    bar_lgkm();

    // ---- GEMM2: oacc[rf][cg] = OUT[32w+16rf+4g+r][n0+16cg+m], split-bf16 ----
    f32x4 oacc[2][4];
#pragma unroll
    for (int rf = 0; rf < 2; ++rf)
#pragma unroll
        for (int cg = 0; cg < 4; ++cg) oacc[rf][cg] = (f32x4)0.f;

#pragma unroll
    for (int kc = 0; kc < 8; ++kc) {
        bf16x8 ah[2], al[2];
        ah[0] = mh0[kc];                         // prefetched M-hi rf=0
        ah[1] = *(const bf16x8*)(Mh + 4096 + kc * 512);
        al[0] = *(const bf16x8*)(Ml + kc * 512);
        al[1] = *(const bf16x8*)(Ml + 4096 + kc * 512);
        bf16x8 bh[4], bl[4];
#pragma unroll
        for (int cg = 0; cg < 4; ++cg) {
            int n = 16 * cg + m;
            int off = (n * 512 + (32 * kc + 8 * g) * 2) ^ ((n & 31) << 4);
            bh[cg] = *(const bf16x8*)(L0 + off);
            bl[cg] = *(const bf16x8*)(L1 + off);
        }
#pragma unroll
        for (int rf = 0; rf < 2; ++rf)
#pragma unroll
            for (int cg = 0; cg < 4; ++cg) {
                oacc[rf][cg] = MFMA16(ah[rf], bh[cg], oacc[rf][cg]);
                oacc[rf][cg] = MFMA16(ah[rf], bl[cg], oacc[rf][cg]);
                oacc[rf][cg] = MFMA16(al[rf], bh[cg], oacc[rf][cg]);
            }
    }

    // ---- epilogue: + bias, nt stores ----
#pragma unroll
    for (int rf = 0; rf < 2; ++rf) {
        float bb[4];
#pragma unroll
        for (int r = 0; r < 4; ++r) bb[r] = bout[32 * w + 16 * rf + 4 * g + r];
#pragma unroll
        for (int cg = 0; cg < 4; ++cg) {
            int n = n0 + 16 * cg + m;
#pragma unroll
            for (int r = 0; r < 4; ++r) {
                int o = 32 * w + 16 * rf + 4 * g + r;
                __builtin_nontemporal_store(oacc[rf][cg][r] + bb[r], &og[(size_t)o * FN + n]);
            }
        }
    }
}

extern "C" void kernel_launch(void* const* d_in, const int* in_sizes, int n_in,
                              void* d_out, int out_size, void* d_ws, size_t ws_size,
                              hipStream_t stream) {
    const float* x    = (const float*)d_in[0];
    const float* wqkv = (const float*)d_in[1];
    const float* wout = (const float*)d_in[2];
    const float* bout = (const float*)d_in[3];
    float* out = (float*)d_out;
    float* ws  = (float*)d_ws;

    size_t partc_elems = (size_t)BF * NS * 256 * 32;
    size_t partz_elems = (size_t)BF * NS * 256;
    float* partC = ws;
    float* partz = ws + partc_elems;
    unsigned short* U = (unsigned short*)(ws + partc_elems + partz_elems);
    unsigned short* wqfhi  = U + WQHI_O;
    unsigned short* wqflo  = U + WQLO_O;
    unsigned short* wkvfhi = U + WKVHI_O;
    unsigned short* wkvflo = U + WKVLO_O;
    unsigned short* Mfhi   = U + MHI_O;
    unsigned short* Mflo   = U + MLO_O;

    k0_prep<<<768, 256, 0, stream>>>(wqkv, wqfhi, wqflo, wkvfhi, wkvflo);
    k1_mfma<<<dim3(NS, BF), 512, 0, stream>>>(x, wkvfhi, wkvflo, partC, partz);
    k2_M<<<dim3(BF, HEADS), 256, 0, stream>>>(partC, partz, wout, Mfhi, Mflo, NS);
    k3_mfma<<<dim3(NN / TN3, BF), 512, 0, stream>>>(x, wqfhi, wqflo, Mfhi, Mflo, bout, out);
}

// Round 13
// 294.631 us; speedup vs baseline: 1.7076x; 1.7076x over previous
//
#include <hip/hip_runtime.h>
#include <hip/hip_bf16.h>
#include <math.h>

// Problem constants
#define BB    2
#define CC    256
#define FF    16
#define NN    4096      // 64*64 spatial
#define FN    (FF*NN)   // 65536
#define BF    32        // BB*FF
#define HEADS 8
#define DH    32
#define HID   256
#define NS    8         // n-range splits in K1
#define TN1   64        // n tile width (K1)
#define TN3   64        // n tile width (K3)
#define SCALEF 0.17677669529663687f   // 32^-0.5

// ushort offsets within U (fragment-major):
// WQF  [w:8][rf:2][kc:8][g:4][m:16][i:8]           = 65536
// WKVF [w:8][cg:4][kc:8][g:4][m:16][i:8]           = 131072
// MF   [bf:32][w:8][rf:2][kc:8][g:4][m:16][i:8]    = BF*65536
#define WQHI_O  0
#define WQLO_O  65536
#define WKVHI_O 131072
#define WKVLO_O 262144
#define MHI_O   393216
#define MLO_O   (393216 + BF*256*256)
#define USH_ELEMS (393216 + 2*BF*256*256)   // 4,587,520 ushorts

typedef __attribute__((ext_vector_type(8))) short bf16x8;
typedef __attribute__((ext_vector_type(8))) unsigned short u16x8;
typedef __attribute__((ext_vector_type(4))) unsigned short u16x4;
typedef __attribute__((ext_vector_type(4))) float f32x4;

#define MFMA16(a, b, c) __builtin_amdgcn_mfma_f32_16x16x32_bf16((a), (b), (c), 0, 0, 0)

// Raw barrier: LDS-visibility only (lgkmcnt) — global loads stay in flight.
__device__ __forceinline__ void bar_lgkm() {
    asm volatile("s_waitcnt lgkmcnt(0)" ::: "memory");
    __builtin_amdgcn_s_barrier();
    asm volatile("" ::: "memory");
}

// HW bf16 convert (RNE).
__device__ inline unsigned short f2bf(float f) {
    union { __hip_bfloat16 h; unsigned short u; } cv;
    cv.h = __float2bfloat16(f);
    return cv.u;
}
__device__ inline float bf2f(unsigned short h) {
    return __uint_as_float(((unsigned int)h) << 16);
}

// K0: split w_qkv into bf16 hi/lo, FRAGMENT-MAJOR (lane l reads [l*8 .. l*8+8)).
__global__ __launch_bounds__(256) void k0_prep(const float* __restrict__ wqkv,
                                               unsigned short* __restrict__ wqfhi,
                                               unsigned short* __restrict__ wqflo,
                                               unsigned short* __restrict__ wkvfhi,
                                               unsigned short* __restrict__ wkvflo) {
    int idx = blockIdx.x * 256 + threadIdx.x;   // 0 .. 768*256
    int o = idx >> 8;
    int c = idx & 255;
    float v = wqkv[idx];
    unsigned short hv = f2bf(v);
    unsigned short lv = f2bf(v - bf2f(hv));
    int kc = c >> 5, g = (c >> 3) & 3, i = c & 7;
    if (o < 256) {
        int w = o >> 5, rf = (o >> 4) & 1, m = o & 15;
        int fi = w * 8192 + rf * 4096 + kc * 512 + g * 128 + m * 8 + i;
        wqfhi[fi] = hv;
        wqflo[fi] = lv;
    } else {
        int r = o - 256;
        int w = r >> 6, cg = (r >> 4) & 3, m = r & 15;
        int fi = w * 16384 + cg * 4096 + kc * 512 + g * 128 + m * 8 + i;
        wkvfhi[fi] = hv;
        wkvflo[fi] = lv;
    }
}

// K1 (MFMA, per-head waves): wave = head h. Per (bf, ns), per 64-col tile:
//   GEMM1: D[n][kv] for head h's 32 k-rows + 32 v-rows (split-bf16, 4rf x 4cg)
//   exp/z on k-halves (in reg) -> P/V to WAVE-PRIVATE LDS (no barriers) ->
//   ctx MFMA over 2 n-chunks -> [restage XT || nt-prefetch].
// (exact round-10 version: 131.5 us, VGPR 128 no spill)
__global__ __launch_bounds__(512, 2) void k1_mfma(const float* __restrict__ x,
                                                  const unsigned short* __restrict__ wkvfhi,
                                                  const unsigned short* __restrict__ wkvflo,
                                                  float* __restrict__ partC,
                                                  float* __restrict__ partz) {
    const int ns = blockIdx.x;      // 0..NS-1
    const int bf = blockIdx.y;
    const int b = bf >> 4, f = bf & 15;
    const float* xbase = x + (size_t)b * (CC * FN) + (size_t)f * NN;
    const int t = threadIdx.x;
    const int w = t >> 6;           // wave 0..7 = head h
    const int l = t & 63;
    const int g = l >> 4, m = l & 15;

    const int strip = NN / NS;      // 512
    const int ntiles = strip / TN1; // 8
    const int nbase = ns * strip;

    // LDS: XT 64 KiB (2 planes x 32 KiB) + wave-private PV 80 KiB (8 x 10 KiB)
    __shared__ __align__(16) char LDS[147456];
    char* X0 = LDS;                 // XT hi [64 n][256 c] bf16, swizzled (rows 512B)
    char* X1 = LDS + 32768;         // XT lo
    char* PV0 = LDS + 65536 + w * 10240;          // hi
    char* PV1 = LDS + 65536 + w * 10240 + 5120;   // lo

    f32x4 ctx[2][2];
#pragma unroll
    for (int df = 0; df < 2; ++df)
#pragma unroll
        for (int ef = 0; ef < 2; ++ef) ctx[df][ef] = (f32x4)0.f;
    float zacc[2] = {0.f, 0.f};

    // fragment-major weight bases: head h k-rows (32h..32h+32), v-rows (+256)
    const int kbase = (w >> 1) * 16384 + (w & 1) * 8192 + l * 8;
    const int vbase = (4 + (w >> 1)) * 16384 + (w & 1) * 8192 + l * 8;
    const unsigned short* bkh = wkvfhi + kbase;
    const unsigned short* bkl = wkvflo + kbase;
    const unsigned short* bvh = wkvfhi + vbase;
    const unsigned short* bvl = wkvflo + vbase;

    // staging geometry: lane owns column nl = l, 32 c's starting at w*32
    const int nl = l;
    const int c0 = w * 32;

    // ---- prologue: nt-load tile 0, stage it, nt-prefetch tile 1 ----
    float v[32];
#pragma unroll
    for (int i = 0; i < 32; ++i)
        v[i] = __builtin_nontemporal_load(&xbase[(size_t)(c0 + i) * FN + nbase + nl]);

#pragma unroll
    for (int qq = 0; qq < 4; ++qq) {
        u16x8 vh, vl;
#pragma unroll
        for (int i = 0; i < 8; ++i) {
            float fv = v[qq * 8 + i];
            unsigned short hv = f2bf(fv);
            vh[i] = hv;
            vl[i] = f2bf(fv - bf2f(hv));
        }
        int off = (nl * 512 + (c0 + qq * 8) * 2) ^ ((nl & 31) << 4);
        *(u16x8*)(X0 + off) = vh;
        *(u16x8*)(X1 + off) = vl;
    }
    if (ntiles > 1) {
#pragma unroll
        for (int i = 0; i < 32; ++i)
            v[i] = __builtin_nontemporal_load(&xbase[(size_t)(c0 + i) * FN + nbase + TN1 + nl]);
    }
    bar_lgkm();   // B1: XT(0) visible; prefetch(1) stays in flight

    for (int tile = 0; tile < ntiles; ++tile) {
        // ---- GEMM1: acc[rf][cg] = D[n=16rf+4g+r][head h kv], split-bf16 ----
        // cg 0,1: k-rows 32h+16cg+m ; cg 2,3: v-rows 32h+16(cg-2)+m
        f32x4 acc[4][4];
#pragma unroll
        for (int rf = 0; rf < 4; ++rf)
#pragma unroll
            for (int cg = 0; cg < 4; ++cg) acc[rf][cg] = (f32x4)0.f;

#pragma unroll 2
        for (int kc = 0; kc < 8; ++kc) {
            bf16x8 ah[4], al[4];
#pragma unroll
            for (int rf = 0; rf < 4; ++rf) {
                int n = 16 * rf + m;
                int off = (n * 512 + (32 * kc + 8 * g) * 2) ^ ((n & 31) << 4);
                ah[rf] = *(const bf16x8*)(X0 + off);
                al[rf] = *(const bf16x8*)(X1 + off);
            }
            bf16x8 bh[4], bl[4];
            bh[0] = *(const bf16x8*)(bkh + kc * 512);
            bl[0] = *(const bf16x8*)(bkl + kc * 512);
            bh[1] = *(const bf16x8*)(bkh + 4096 + kc * 512);
            bl[1] = *(const bf16x8*)(bkl + 4096 + kc * 512);
            bh[2] = *(const bf16x8*)(bvh + kc * 512);
            bl[2] = *(const bf16x8*)(bvl + kc * 512);
            bh[3] = *(const bf16x8*)(bvh + 4096 + kc * 512);
            bl[3] = *(const bf16x8*)(bvl + 4096 + kc * 512);
#pragma unroll
            for (int rf = 0; rf < 4; ++rf)
#pragma unroll
                for (int cg = 0; cg < 4; ++cg) {
                    acc[rf][cg] = MFMA16(ah[rf], bh[cg], acc[rf][cg]);
                    acc[rf][cg] = MFMA16(ah[rf], bl[cg], acc[rf][cg]);
                    acc[rf][cg] = MFMA16(al[rf], bh[cg], acc[rf][cg]);
                }
        }
        bar_lgkm();   // B2: all XT reads done -> XT region free for restage

        // ---- exp + z on k-halves (cg 0,1), register-only ----
#pragma unroll
        for (int cg = 0; cg < 2; ++cg) {
            float s = 0.f;
#pragma unroll
            for (int rf = 0; rf < 4; ++rf)
#pragma unroll
                for (int r = 0; r < 4; ++r) {
                    float e = __expf(acc[rf][cg][r]);
                    acc[rf][cg][r] = e;
                    s += e;
                }
            s += __shfl_xor(s, 16);
            s += __shfl_xor(s, 32);
            zacc[cg] += s;
        }

        // ---- PV: wave-private, 2 n-chunks of 32, no barriers ----
#pragma unroll
        for (int ks = 0; ks < 2; ++ks) {
#pragma unroll
            for (int rfh = 0; rfh < 2; ++rfh) {
                int rf = 2 * ks + rfh;
#pragma unroll
                for (int cg = 0; cg < 4; ++cg) {
                    int row = 16 * cg + m;
                    u16x4 vh4, vl4;
#pragma unroll
                    for (int r = 0; r < 4; ++r) {
                        float fv = acc[rf][cg][r];
                        unsigned short hv = f2bf(fv);
                        vh4[r] = hv;
                        vl4[r] = f2bf(fv - bf2f(hv));
                    }
                    int off = row * 80 + 32 * rfh + 8 * g;
                    *(u16x4*)(PV0 + off) = vh4;
                    *(u16x4*)(PV1 + off) = vl4;
                }
            }
            bf16x8 ph[2], pl[2], vh_[2], vl_[2];
#pragma unroll
            for (int df = 0; df < 2; ++df) {
                int off = (16 * df + m) * 80 + 16 * g;
                ph[df] = *(const bf16x8*)(PV0 + off);
                pl[df] = *(const bf16x8*)(PV1 + off);
            }
#pragma unroll
            for (int ef = 0; ef < 2; ++ef) {
                int off = (32 + 16 * ef + m) * 80 + 16 * g;
                vh_[ef] = *(const bf16x8*)(PV0 + off);
                vl_[ef] = *(const bf16x8*)(PV1 + off);
            }
#pragma unroll
            for (int df = 0; df < 2; ++df)
#pragma unroll
                for (int ef = 0; ef < 2; ++ef) {
                    ctx[df][ef] = MFMA16(ph[df], vh_[ef], ctx[df][ef]);
                    ctx[df][ef] = MFMA16(ph[df], vl_[ef], ctx[df][ef]);
                    ctx[df][ef] = MFMA16(pl[df], vh_[ef], ctx[df][ef]);
                }
        }

        // ---- restage next tile's XT, nt-prefetch tile+2 ----
        if (tile + 1 < ntiles) {
#pragma unroll
            for (int qq = 0; qq < 4; ++qq) {
                u16x8 vh, vl;
#pragma unroll
                for (int i = 0; i < 8; ++i) {
                    float fv = v[qq * 8 + i];
                    unsigned short hv = f2bf(fv);
                    vh[i] = hv;
                    vl[i] = f2bf(fv - bf2f(hv));
                }
                int off = (nl * 512 + (c0 + qq * 8) * 2) ^ ((nl & 31) << 4);
                *(u16x8*)(X0 + off) = vh;
                *(u16x8*)(X1 + off) = vl;
            }
            if (tile + 2 < ntiles) {
                int n0n = nbase + (tile + 2) * TN1;
#pragma unroll
                for (int i = 0; i < 32; ++i)
                    v[i] = __builtin_nontemporal_load(&xbase[(size_t)(c0 + i) * FN + n0n + nl]);
            }
            bar_lgkm();   // B1': next XT visible
        }
    }

    // ---- write partials ----
    if (g == 0) {
#pragma unroll
        for (int cg = 0; cg < 2; ++cg)
            partz[(size_t)(bf * NS + ns) * 256 + 32 * w + 16 * cg + m] = zacc[cg];
    }
#pragma unroll
    for (int df = 0; df < 2; ++df)
#pragma unroll
        for (int ef = 0; ef < 2; ++ef)
#pragma unroll
            for (int r = 0; r < 4; ++r) {
                int row = 32 * w + 16 * df + 4 * g + r;
                int col = 16 * ef + m;
                partC[((size_t)(bf * NS + ns) * 256 + row) * 32 + col] = ctx[df][ef][r];
            }
}

// K2: per (bf, head): merge partials -> ctx (SCALE/z folded);
// M[o][32h+d] = sum_e wout[o][32h+e]*ctx[d][e], bf16 hi/lo FRAGMENT-MAJOR.
__global__ __launch_bounds__(256) void k2_M(const float* __restrict__ partC,
                                            const float* __restrict__ partz,
                                            const float* __restrict__ wout,
                                            unsigned short* __restrict__ Mhi,
                                            unsigned short* __restrict__ Mlo,
                                            int nsplit) {
    const int bf = blockIdx.x;
    const int h  = blockIdx.y;
    const int t  = threadIdx.x;

    __shared__ float ctxs[32][33];
    __shared__ float zs[32];

    if (t < 32) {
        float z = 0.f;
        for (int ns2 = 0; ns2 < nsplit; ++ns2)
            z += partz[(size_t)(bf * nsplit + ns2) * 256 + 32 * h + t];
        zs[t] = SCALEF / z;
    }
    {
        const int d = t & 31, eg = t >> 5;
        float4 c = make_float4(0.f, 0.f, 0.f, 0.f);
        for (int ns2 = 0; ns2 < nsplit; ++ns2) {
            const float4 p = *(const float4*)&partC[
                ((size_t)(bf * nsplit + ns2) * 256 + 32 * h + d) * 32 + 4 * eg];
            c.x += p.x; c.y += p.y; c.z += p.z; c.w += p.w;
        }
        __syncthreads();   // zs ready
        float zi = zs[d];
        ctxs[d][4 * eg + 0] = c.x * zi;
        ctxs[d][4 * eg + 1] = c.y * zi;
        ctxs[d][4 * eg + 2] = c.z * zi;
        ctxs[d][4 * eg + 3] = c.w * zi;
    }
    __syncthreads();

    const int o = t;
    float wo[32];
#pragma unroll
    for (int j = 0; j < 8; ++j) {
        float4 w4 = *(const float4*)&wout[o * 256 + 32 * h + 4 * j];
        wo[4 * j + 0] = w4.x;
        wo[4 * j + 1] = w4.y;
        wo[4 * j + 2] = w4.z;
        wo[4 * j + 3] = w4.w;
    }
    const int wq = o >> 5, rf = (o >> 4) & 1, mm = o & 15;
    const size_t fbase = (size_t)bf * 65536 + wq * 8192 + rf * 4096 + h * 512 + mm * 8;
#pragma unroll
    for (int d = 0; d < 32; ++d) {
        float mv = 0.f;
#pragma unroll
        for (int e = 0; e < 32; ++e) mv += wo[e] * ctxs[d][e];
        unsigned short hv = f2bf(mv);
        unsigned short lv = f2bf(mv - bf2f(hv));
        size_t fi = fbase + (size_t)(d >> 3) * 128 + (d & 7);
        Mhi[fi] = hv;
        Mlo[fi] = lv;
    }
}

// K3 (MFMA): per (bf, 64-col tile). M-hi(rf=0) prefetched at kernel start;
// raw lgkm barriers keep those loads in flight across the phase boundaries.
__global__ __launch_bounds__(512, 4) void k3_mfma(const float* __restrict__ x,
                                                  const unsigned short* __restrict__ wqfhi,
                                                  const unsigned short* __restrict__ wqflo,
                                                  const unsigned short* __restrict__ mfhi,
                                                  const unsigned short* __restrict__ mflo,
                                                  const float* __restrict__ bout,
                                                  float* __restrict__ out) {
    const int tile = blockIdx.x;    // 0..63
    const int bf = blockIdx.y;
    const int b = bf >> 4, f = bf & 15;
    const size_t xoff = (size_t)b * (CC * FN) + (size_t)f * NN;
    const float* xg = x + xoff;
    float* og = out + xoff;
    const int n0 = tile * TN3;
    const int t = threadIdx.x;
    const int w = t >> 6;           // wave 0..7 (= head for GEMM1)
    const int l = t & 63;
    const int g = l >> 4, m = l & 15;

    __shared__ unsigned short lds[2][64][256];
    char* L0 = (char*)&lds[0][0][0];
    char* L1 = (char*)&lds[1][0][0];

    const unsigned short* Mh = mfhi + (size_t)bf * 65536 + w * 8192 + l * 8;
    const unsigned short* Ml = mflo + (size_t)bf * 65536 + w * 8192 + l * 8;

    // ---- stage: transpose X[c][n] -> XT[n][c] bf16 hi/lo, swizzled (nt loads) ----
#pragma unroll
    for (int q = 0; q < 4; ++q) {
        int c0 = 32 * w + 8 * q;
        float v[8];
#pragma unroll
        for (int i = 0; i < 8; ++i)
            v[i] = __builtin_nontemporal_load(&xg[(size_t)(c0 + i) * FN + n0 + l]);
        u16x8 vh, vl;
#pragma unroll
        for (int i = 0; i < 8; ++i) {
            unsigned short hv = f2bf(v[i]);
            vh[i] = hv;
            vl[i] = f2bf(v[i] - bf2f(hv));
        }
        int off = (l * 512 + c0 * 2) ^ ((l & 31) << 4);
        *(u16x8*)(L0 + off) = vh;
        *(u16x8*)(L1 + off) = vl;
    }

    // ---- prefetch GEMM2's M-hi rf=0 fragments (in flight across barriers) ----
    bf16x8 mh0[8];
#pragma unroll
    for (int kc = 0; kc < 8; ++kc) mh0[kc] = *(const bf16x8*)(Mh + kc * 512);

    bar_lgkm();

    // fragment-major A bases
    const unsigned short* aqh = wqfhi + w * 8192 + l * 8;
    const unsigned short* aql = wqflo + w * 8192 + l * 8;

    // ---- GEMM1: qacc[rf][cg] = Q[32w+16rf+4g+r][n0+16cg+m], split-bf16 ----
    f32x4 qacc[2][4];
#pragma unroll
    for (int rf = 0; rf < 2; ++rf)
#pragma unroll
        for (int cg = 0; cg < 4; ++cg) qacc[rf][cg] = (f32x4)0.f;

#pragma unroll
    for (int kc = 0; kc < 8; ++kc) {
        bf16x8 ah[2], al[2];
#pragma unroll
        for (int rf = 0; rf < 2; ++rf) {
            ah[rf] = *(const bf16x8*)(aqh + rf * 4096 + kc * 512);
            al[rf] = *(const bf16x8*)(aql + rf * 4096 + kc * 512);
        }
        bf16x8 bh[4], bl[4];
#pragma unroll
        for (int cg = 0; cg < 4; ++cg) {
            int n = 16 * cg + m;
            int off = (n * 512 + (32 * kc + 8 * g) * 2) ^ ((n & 31) << 4);
            bh[cg] = *(const bf16x8*)(L0 + off);
            bl[cg] = *(const bf16x8*)(L1 + off);
        }
#pragma unroll
        for (int rf = 0; rf < 2; ++rf)
#pragma unroll
            for (int cg = 0; cg < 4; ++cg) {
                qacc[rf][cg] = MFMA16(ah[rf], bh[cg], qacc[rf][cg]);
                qacc[rf][cg] = MFMA16(ah[rf], bl[cg], qacc[rf][cg]);
                qacc[rf][cg] = MFMA16(al[rf], bh[cg], qacc[rf][cg]);
            }
    }

    // ---- softmax over d (in-register; head = w) ----
    float zinv[4];
#pragma unroll
    for (int cg = 0; cg < 4; ++cg) {
        float s = 0.f;
#pragma unroll
        for (int rf = 0; rf < 2; ++rf)
#pragma unroll
            for (int r = 0; r < 4; ++r) {
                float e = __expf(qacc[rf][cg][r]);
                qacc[rf][cg][r] = e;
                s += e;
            }
        s += __shfl_xor(s, 16);
        s += __shfl_xor(s, 32);
        zinv[cg] = 1.f / s;   // SCALE folded into M
    }

    bar_lgkm();

    // ---- write QsmT[n][hd] bf16 hi/lo (aliased over XT planes) ----
#pragma unroll
    for (int rf = 0; rf < 2; ++rf)
#pragma unroll
        for (int cg = 0; cg < 4; ++cg) {
            int n = 16 * cg + m;
            int hd0 = 32 * w + 16 * rf + 4 * g;
            u16x4 vh, vl;
#pragma unroll
            for (int r = 0; r < 4; ++r) {
                float qv = qacc[rf][cg][r] * zinv[cg];
                unsigned short hv = f2bf(qv);
                vh[r] = hv;
                vl[r] = f2bf(qv - bf2f(hv));
            }
            int off = (n * 512 + hd0 * 2) ^ ((n & 31) << 4);
            *(u16x4*)(L0 + off) = vh;
            *(u16x4*)(L1 + off) = vl;
        }
    bar_lgkm();

    // ---- GEMM2: oacc[rf][cg] = OUT[32w+16rf+4g+r][n0+16cg+m], split-bf16 ----
    f32x4 oacc[2][4];
#pragma unroll
    for (int rf = 0; rf < 2; ++rf)
#pragma unroll
        for (int cg = 0; cg < 4; ++cg) oacc[rf][cg] = (f32x4)0.f;

#pragma unroll
    for (int kc = 0; kc < 8; ++kc) {
        bf16x8 ah[2], al[2];
        ah[0] = mh0[kc];                         // prefetched M-hi rf=0
        ah[1] = *(const bf16x8*)(Mh + 4096 + kc * 512);
        al[0] = *(const bf16x8*)(Ml + kc * 512);
        al[1] = *(const bf16x8*)(Ml + 4096 + kc * 512);
        bf16x8 bh[4], bl[4];
#pragma unroll
        for (int cg = 0; cg < 4; ++cg) {
            int n = 16 * cg + m;
            int off = (n * 512 + (32 * kc + 8 * g) * 2) ^ ((n & 31) << 4);
            bh[cg] = *(const bf16x8*)(L0 + off);
            bl[cg] = *(const bf16x8*)(L1 + off);
        }
#pragma unroll
        for (int rf = 0; rf < 2; ++rf)
#pragma unroll
            for (int cg = 0; cg < 4; ++cg) {
                oacc[rf][cg] = MFMA16(ah[rf], bh[cg], oacc[rf][cg]);
                oacc[rf][cg] = MFMA16(ah[rf], bl[cg], oacc[rf][cg]);
                oacc[rf][cg] = MFMA16(al[rf], bh[cg], oacc[rf][cg]);
            }
    }

    // ---- epilogue: + bias, nt stores ----
#pragma unroll
    for (int rf = 0; rf < 2; ++rf) {
        float bb[4];
#pragma unroll
        for (int r = 0; r < 4; ++r) bb[r] = bout[32 * w + 16 * rf + 4 * g + r];
#pragma unroll
        for (int cg = 0; cg < 4; ++cg) {
            int n = n0 + 16 * cg + m;
#pragma unroll
            for (int r = 0; r < 4; ++r) {
                int o = 32 * w + 16 * rf + 4 * g + r;
                __builtin_nontemporal_store(oacc[rf][cg][r] + bb[r], &og[(size_t)o * FN + n]);
            }
        }
    }
}

extern "C" void kernel_launch(void* const* d_in, const int* in_sizes, int n_in,
                              void* d_out, int out_size, void* d_ws, size_t ws_size,
                              hipStream_t stream) {
    const float* x    = (const float*)d_in[0];
    const float* wqkv = (const float*)d_in[1];
    const float* wout = (const float*)d_in[2];
    const float* bout = (const float*)d_in[3];
    float* out = (float*)d_out;
    float* ws  = (float*)d_ws;

    size_t partc_elems = (size_t)BF * NS * 256 * 32;
    size_t partz_elems = (size_t)BF * NS * 256;
    float* partC = ws;
    float* partz = ws + partc_elems;
    unsigned short* U = (unsigned short*)(ws + partc_elems + partz_elems);
    unsigned short* wqfhi  = U + WQHI_O;
    unsigned short* wqflo  = U + WQLO_O;
    unsigned short* wkvfhi = U + WKVHI_O;
    unsigned short* wkvflo = U + WKVLO_O;
    unsigned short* Mfhi   = U + MHI_O;
    unsigned short* Mflo   = U + MLO_O;

    k0_prep<<<768, 256, 0, stream>>>(wqkv, wqfhi, wqflo, wkvfhi, wkvflo);
    k1_mfma<<<dim3(NS, BF), 512, 0, stream>>>(x, wkvfhi, wkvflo, partC, partz);
    k2_M<<<dim3(BF, HEADS), 256, 0, stream>>>(partC, partz, wout, Mfhi, Mflo, NS);
    k3_mfma<<<dim3(NN / TN3, BF), 512, 0, stream>>>(x, wqfhi, wqflo, Mfhi, Mflo, bout, out);
}

// Round 14
// 250.015 us; speedup vs baseline: 2.0123x; 1.1785x over previous
//
#include <hip/hip_runtime.h>
#include <hip/hip_bf16.h>
#include <math.h>

// Problem constants
#define BB    2
#define CC    256
#define FF    16
#define NN    4096      // 64*64 spatial
#define FN    (FF*NN)   // 65536
#define BF    32        // BB*FF
#define HEADS 8
#define DH    32
#define HID   256
#define NS    8         // n-range splits in K1
#define TN1   64        // n tile width (K1)
#define TN3   64        // n tile width (K3)
#define SCALEF 0.17677669529663687f   // 32^-0.5

// ushort offsets within U (fragment-major):
// WQF  [w:8][rf:2][kc:8][g:4][m:16][i:8]           = 65536
// WKVF [w:8][cg:4][kc:8][g:4][m:16][i:8]           = 131072
// MF   [bf:32][w:8][rf:2][kc:8][g:4][m:16][i:8]    = BF*65536
#define WQHI_O  0
#define WQLO_O  65536
#define WKVHI_O 131072
#define WKVLO_O 262144
#define MHI_O   393216
#define MLO_O   (393216 + BF*256*256)
#define USH_ELEMS (393216 + 2*BF*256*256)   // 4,587,520 ushorts

typedef __attribute__((ext_vector_type(8))) short bf16x8;
typedef __attribute__((ext_vector_type(8))) unsigned short u16x8;
typedef __attribute__((ext_vector_type(4))) unsigned short u16x4;
typedef __attribute__((ext_vector_type(4))) float f32x4;

#define MFMA16(a, b, c) __builtin_amdgcn_mfma_f32_16x16x32_bf16((a), (b), (c), 0, 0, 0)

// Raw barrier: LDS-visibility only (lgkmcnt) — global loads stay in flight.
__device__ __forceinline__ void bar_lgkm() {
    asm volatile("s_waitcnt lgkmcnt(0)" ::: "memory");
    __builtin_amdgcn_s_barrier();
    asm volatile("" ::: "memory");
}

// HW bf16 convert (RNE).
__device__ inline unsigned short f2bf(float f) {
    union { __hip_bfloat16 h; unsigned short u; } cv;
    cv.h = __float2bfloat16(f);
    return cv.u;
}
__device__ inline float bf2f(unsigned short h) {
    return __uint_as_float(((unsigned int)h) << 16);
}

// K0: split w_qkv into bf16 hi/lo, FRAGMENT-MAJOR (lane l reads [l*8 .. l*8+8)).
__global__ __launch_bounds__(256) void k0_prep(const float* __restrict__ wqkv,
                                               unsigned short* __restrict__ wqfhi,
                                               unsigned short* __restrict__ wqflo,
                                               unsigned short* __restrict__ wkvfhi,
                                               unsigned short* __restrict__ wkvflo) {
    int idx = blockIdx.x * 256 + threadIdx.x;   // 0 .. 768*256
    int o = idx >> 8;
    int c = idx & 255;
    float v = wqkv[idx];
    unsigned short hv = f2bf(v);
    unsigned short lv = f2bf(v - bf2f(hv));
    int kc = c >> 5, g = (c >> 3) & 3, i = c & 7;
    if (o < 256) {
        int w = o >> 5, rf = (o >> 4) & 1, m = o & 15;
        int fi = w * 8192 + rf * 4096 + kc * 512 + g * 128 + m * 8 + i;
        wqfhi[fi] = hv;
        wqflo[fi] = lv;
    } else {
        int r = o - 256;
        int w = r >> 6, cg = (r >> 4) & 3, m = r & 15;
        int fi = w * 16384 + cg * 4096 + kc * 512 + g * 128 + m * 8 + i;
        wkvfhi[fi] = hv;
        wkvflo[fi] = lv;
    }
}

// K1 (MFMA, per-head waves): wave = head h. Per (bf, ns), per 64-col tile:
//   GEMM1: D[n][kv] for head h's 32 k-rows + 32 v-rows (split-bf16, 4rf x 4cg)
//   exp/z on k-halves (in reg) -> P/V to WAVE-PRIVATE LDS (no barriers) ->
//   ctx MFMA over 2 n-chunks -> [restage XT || nt-prefetch].
// (exact round-10 version: 131.5 us, VGPR 128 no spill)
__global__ __launch_bounds__(512, 2) void k1_mfma(const float* __restrict__ x,
                                                  const unsigned short* __restrict__ wkvfhi,
                                                  const unsigned short* __restrict__ wkvflo,
                                                  float* __restrict__ partC,
                                                  float* __restrict__ partz) {
    const int ns = blockIdx.x;      // 0..NS-1
    const int bf = blockIdx.y;
    const int b = bf >> 4, f = bf & 15;
    const float* xbase = x + (size_t)b * (CC * FN) + (size_t)f * NN;
    const int t = threadIdx.x;
    const int w = t >> 6;           // wave 0..7 = head h
    const int l = t & 63;
    const int g = l >> 4, m = l & 15;

    const int strip = NN / NS;      // 512
    const int ntiles = strip / TN1; // 8
    const int nbase = ns * strip;

    // LDS: XT 64 KiB (2 planes x 32 KiB) + wave-private PV 80 KiB (8 x 10 KiB)
    __shared__ __align__(16) char LDS[147456];
    char* X0 = LDS;                 // XT hi [64 n][256 c] bf16, swizzled (rows 512B)
    char* X1 = LDS + 32768;         // XT lo
    char* PV0 = LDS + 65536 + w * 10240;          // hi
    char* PV1 = LDS + 65536 + w * 10240 + 5120;   // lo

    f32x4 ctx[2][2];
#pragma unroll
    for (int df = 0; df < 2; ++df)
#pragma unroll
        for (int ef = 0; ef < 2; ++ef) ctx[df][ef] = (f32x4)0.f;
    float zacc[2] = {0.f, 0.f};

    // fragment-major weight bases: head h k-rows (32h..32h+32), v-rows (+256)
    const int kbase = (w >> 1) * 16384 + (w & 1) * 8192 + l * 8;
    const int vbase = (4 + (w >> 1)) * 16384 + (w & 1) * 8192 + l * 8;
    const unsigned short* bkh = wkvfhi + kbase;
    const unsigned short* bkl = wkvflo + kbase;
    const unsigned short* bvh = wkvfhi + vbase;
    const unsigned short* bvl = wkvflo + vbase;

    // staging geometry: lane owns column nl = l, 32 c's starting at w*32
    const int nl = l;
    const int c0 = w * 32;

    // ---- prologue: nt-load tile 0, stage it, nt-prefetch tile 1 ----
    float v[32];
#pragma unroll
    for (int i = 0; i < 32; ++i)
        v[i] = __builtin_nontemporal_load(&xbase[(size_t)(c0 + i) * FN + nbase + nl]);

#pragma unroll
    for (int qq = 0; qq < 4; ++qq) {
        u16x8 vh, vl;
#pragma unroll
        for (int i = 0; i < 8; ++i) {
            float fv = v[qq * 8 + i];
            unsigned short hv = f2bf(fv);
            vh[i] = hv;
            vl[i] = f2bf(fv - bf2f(hv));
        }
        int off = (nl * 512 + (c0 + qq * 8) * 2) ^ ((nl & 31) << 4);
        *(u16x8*)(X0 + off) = vh;
        *(u16x8*)(X1 + off) = vl;
    }
    if (ntiles > 1) {
#pragma unroll
        for (int i = 0; i < 32; ++i)
            v[i] = __builtin_nontemporal_load(&xbase[(size_t)(c0 + i) * FN + nbase + TN1 + nl]);
    }
    bar_lgkm();   // B1: XT(0) visible; prefetch(1) stays in flight

    for (int tile = 0; tile < ntiles; ++tile) {
        // ---- GEMM1: acc[rf][cg] = D[n=16rf+4g+r][head h kv], split-bf16 ----
        // cg 0,1: k-rows 32h+16cg+m ; cg 2,3: v-rows 32h+16(cg-2)+m
        f32x4 acc[4][4];
#pragma unroll
        for (int rf = 0; rf < 4; ++rf)
#pragma unroll
            for (int cg = 0; cg < 4; ++cg) acc[rf][cg] = (f32x4)0.f;

#pragma unroll 2
        for (int kc = 0; kc < 8; ++kc) {
            bf16x8 ah[4], al[4];
#pragma unroll
            for (int rf = 0; rf < 4; ++rf) {
                int n = 16 * rf + m;
                int off = (n * 512 + (32 * kc + 8 * g) * 2) ^ ((n & 31) << 4);
                ah[rf] = *(const bf16x8*)(X0 + off);
                al[rf] = *(const bf16x8*)(X1 + off);
            }
            bf16x8 bh[4], bl[4];
            bh[0] = *(const bf16x8*)(bkh + kc * 512);
            bl[0] = *(const bf16x8*)(bkl + kc * 512);
            bh[1] = *(const bf16x8*)(bkh + 4096 + kc * 512);
            bl[1] = *(const bf16x8*)(bkl + 4096 + kc * 512);
            bh[2] = *(const bf16x8*)(bvh + kc * 512);
            bl[2] = *(const bf16x8*)(bvl + kc * 512);
            bh[3] = *(const bf16x8*)(bvh + 4096 + kc * 512);
            bl[3] = *(const bf16x8*)(bvl + 4096 + kc * 512);
#pragma unroll
            for (int rf = 0; rf < 4; ++rf)
#pragma unroll
                for (int cg = 0; cg < 4; ++cg) {
                    acc[rf][cg] = MFMA16(ah[rf], bh[cg], acc[rf][cg]);
                    acc[rf][cg] = MFMA16(ah[rf], bl[cg], acc[rf][cg]);
                    acc[rf][cg] = MFMA16(al[rf], bh[cg], acc[rf][cg]);
                }
        }
        bar_lgkm();   // B2: all XT reads done -> XT region free for restage

        // ---- exp + z on k-halves (cg 0,1), register-only ----
#pragma unroll
        for (int cg = 0; cg < 2; ++cg) {
            float s = 0.f;
#pragma unroll
            for (int rf = 0; rf < 4; ++rf)
#pragma unroll
                for (int r = 0; r < 4; ++r) {
                    float e = __expf(acc[rf][cg][r]);
                    acc[rf][cg][r] = e;
                    s += e;
                }
            s += __shfl_xor(s, 16);
            s += __shfl_xor(s, 32);
            zacc[cg] += s;
        }

        // ---- PV: wave-private, 2 n-chunks of 32, no barriers ----
#pragma unroll
        for (int ks = 0; ks < 2; ++ks) {
#pragma unroll
            for (int rfh = 0; rfh < 2; ++rfh) {
                int rf = 2 * ks + rfh;
#pragma unroll
                for (int cg = 0; cg < 4; ++cg) {
                    int row = 16 * cg + m;
                    u16x4 vh4, vl4;
#pragma unroll
                    for (int r = 0; r < 4; ++r) {
                        float fv = acc[rf][cg][r];
                        unsigned short hv = f2bf(fv);
                        vh4[r] = hv;
                        vl4[r] = f2bf(fv - bf2f(hv));
                    }
                    int off = row * 80 + 32 * rfh + 8 * g;
                    *(u16x4*)(PV0 + off) = vh4;
                    *(u16x4*)(PV1 + off) = vl4;
                }
            }
            bf16x8 ph[2], pl[2], vh_[2], vl_[2];
#pragma unroll
            for (int df = 0; df < 2; ++df) {
                int off = (16 * df + m) * 80 + 16 * g;
                ph[df] = *(const bf16x8*)(PV0 + off);
                pl[df] = *(const bf16x8*)(PV1 + off);
            }
#pragma unroll
            for (int ef = 0; ef < 2; ++ef) {
                int off = (32 + 16 * ef + m) * 80 + 16 * g;
                vh_[ef] = *(const bf16x8*)(PV0 + off);
                vl_[ef] = *(const bf16x8*)(PV1 + off);
            }
#pragma unroll
            for (int df = 0; df < 2; ++df)
#pragma unroll
                for (int ef = 0; ef < 2; ++ef) {
                    ctx[df][ef] = MFMA16(ph[df], vh_[ef], ctx[df][ef]);
                    ctx[df][ef] = MFMA16(ph[df], vl_[ef], ctx[df][ef]);
                    ctx[df][ef] = MFMA16(pl[df], vh_[ef], ctx[df][ef]);
                }
        }

        // ---- restage next tile's XT, nt-prefetch tile+2 ----
        if (tile + 1 < ntiles) {
#pragma unroll
            for (int qq = 0; qq < 4; ++qq) {
                u16x8 vh, vl;
#pragma unroll
                for (int i = 0; i < 8; ++i) {
                    float fv = v[qq * 8 + i];
                    unsigned short hv = f2bf(fv);
                    vh[i] = hv;
                    vl[i] = f2bf(fv - bf2f(hv));
                }
                int off = (nl * 512 + (c0 + qq * 8) * 2) ^ ((nl & 31) << 4);
                *(u16x8*)(X0 + off) = vh;
                *(u16x8*)(X1 + off) = vl;
            }
            if (tile + 2 < ntiles) {
                int n0n = nbase + (tile + 2) * TN1;
#pragma unroll
                for (int i = 0; i < 32; ++i)
                    v[i] = __builtin_nontemporal_load(&xbase[(size_t)(c0 + i) * FN + n0n + nl]);
            }
            bar_lgkm();   // B1': next XT visible
        }
    }

    // ---- write partials ----
    if (g == 0) {
#pragma unroll
        for (int cg = 0; cg < 2; ++cg)
            partz[(size_t)(bf * NS + ns) * 256 + 32 * w + 16 * cg + m] = zacc[cg];
    }
#pragma unroll
    for (int df = 0; df < 2; ++df)
#pragma unroll
        for (int ef = 0; ef < 2; ++ef)
#pragma unroll
            for (int r = 0; r < 4; ++r) {
                int row = 32 * w + 16 * df + 4 * g + r;
                int col = 16 * ef + m;
                partC[((size_t)(bf * NS + ns) * 256 + row) * 32 + col] = ctx[df][ef][r];
            }
}

// K2: per (bf, head): merge partials -> ctx (SCALE/z folded);
// M[o][32h+d] = sum_e wout[o][32h+e]*ctx[d][e], bf16 hi/lo FRAGMENT-MAJOR.
__global__ __launch_bounds__(256) void k2_M(const float* __restrict__ partC,
                                            const float* __restrict__ partz,
                                            const float* __restrict__ wout,
                                            unsigned short* __restrict__ Mhi,
                                            unsigned short* __restrict__ Mlo,
                                            int nsplit) {
    const int bf = blockIdx.x;
    const int h  = blockIdx.y;
    const int t  = threadIdx.x;

    __shared__ float ctxs[32][33];
    __shared__ float zs[32];

    if (t < 32) {
        float z = 0.f;
        for (int ns2 = 0; ns2 < nsplit; ++ns2)
            z += partz[(size_t)(bf * nsplit + ns2) * 256 + 32 * h + t];
        zs[t] = SCALEF / z;
    }
    {
        const int d = t & 31, eg = t >> 5;
        float4 c = make_float4(0.f, 0.f, 0.f, 0.f);
        for (int ns2 = 0; ns2 < nsplit; ++ns2) {
            const float4 p = *(const float4*)&partC[
                ((size_t)(bf * nsplit + ns2) * 256 + 32 * h + d) * 32 + 4 * eg];
            c.x += p.x; c.y += p.y; c.z += p.z; c.w += p.w;
        }
        __syncthreads();   // zs ready
        float zi = zs[d];
        ctxs[d][4 * eg + 0] = c.x * zi;
        ctxs[d][4 * eg + 1] = c.y * zi;
        ctxs[d][4 * eg + 2] = c.z * zi;
        ctxs[d][4 * eg + 3] = c.w * zi;
    }
    __syncthreads();

    const int o = t;
    float wo[32];
#pragma unroll
    for (int j = 0; j < 8; ++j) {
        float4 w4 = *(const float4*)&wout[o * 256 + 32 * h + 4 * j];
        wo[4 * j + 0] = w4.x;
        wo[4 * j + 1] = w4.y;
        wo[4 * j + 2] = w4.z;
        wo[4 * j + 3] = w4.w;
    }
    const int wq = o >> 5, rf = (o >> 4) & 1, mm = o & 15;
    const size_t fbase = (size_t)bf * 65536 + wq * 8192 + rf * 4096 + h * 512 + mm * 8;
#pragma unroll
    for (int d = 0; d < 32; ++d) {
        float mv = 0.f;
#pragma unroll
        for (int e = 0; e < 32; ++e) mv += wo[e] * ctxs[d][e];
        unsigned short hv = f2bf(mv);
        unsigned short lv = f2bf(mv - bf2f(hv));
        size_t fi = fbase + (size_t)(d >> 3) * 128 + (d & 7);
        Mhi[fi] = hv;
        Mlo[fi] = lv;
    }
}

// K3 (MFMA): per (bf, 64-col tile):
//   Q = Wq @ X  (split-bf16)  -> in-register softmax over d per column
//   OUT = M @ Qsm (split-bf16) -> + bias -> nt store
// (r11 structure; + s_setprio(1) around MFMA clusters — blocks drift through
//  phases independently at 2 blocks/CU, so the scheduler has roles to arbitrate)
__global__ __launch_bounds__(512, 4) void k3_mfma(const float* __restrict__ x,
                                                  const unsigned short* __restrict__ wqfhi,
                                                  const unsigned short* __restrict__ wqflo,
                                                  const unsigned short* __restrict__ mfhi,
                                                  const unsigned short* __restrict__ mflo,
                                                  const float* __restrict__ bout,
                                                  float* __restrict__ out) {
    const int tile = blockIdx.x;    // 0..63
    const int bf = blockIdx.y;
    const int b = bf >> 4, f = bf & 15;
    const size_t xoff = (size_t)b * (CC * FN) + (size_t)f * NN;
    const float* xg = x + xoff;
    float* og = out + xoff;
    const int n0 = tile * TN3;
    const int t = threadIdx.x;
    const int w = t >> 6;           // wave 0..7 (= head for GEMM1)
    const int l = t & 63;
    const int g = l >> 4, m = l & 15;

    __shared__ unsigned short lds[2][64][256];
    char* L0 = (char*)&lds[0][0][0];
    char* L1 = (char*)&lds[1][0][0];

    // ---- stage: transpose X[c][n] -> XT[n][c] bf16 hi/lo, swizzled (nt loads) ----
#pragma unroll
    for (int q = 0; q < 4; ++q) {
        int c0 = 32 * w + 8 * q;
        float v[8];
#pragma unroll
        for (int i = 0; i < 8; ++i)
            v[i] = __builtin_nontemporal_load(&xg[(size_t)(c0 + i) * FN + n0 + l]);
        u16x8 vh, vl;
#pragma unroll
        for (int i = 0; i < 8; ++i) {
            unsigned short hv = f2bf(v[i]);
            vh[i] = hv;
            vl[i] = f2bf(v[i] - bf2f(hv));
        }
        int off = (l * 512 + c0 * 2) ^ ((l & 31) << 4);
        *(u16x8*)(L0 + off) = vh;
        *(u16x8*)(L1 + off) = vl;
    }
    __syncthreads();

    // fragment-major A bases
    const unsigned short* aqh = wqfhi + w * 8192 + l * 8;
    const unsigned short* aql = wqflo + w * 8192 + l * 8;

    // ---- GEMM1: qacc[rf][cg] = Q[32w+16rf+4g+r][n0+16cg+m], split-bf16 ----
    f32x4 qacc[2][4];
#pragma unroll
    for (int rf = 0; rf < 2; ++rf)
#pragma unroll
        for (int cg = 0; cg < 4; ++cg) qacc[rf][cg] = (f32x4)0.f;

    for (int kc = 0; kc < 8; ++kc) {
        bf16x8 ah[2], al[2];
#pragma unroll
        for (int rf = 0; rf < 2; ++rf) {
            ah[rf] = *(const bf16x8*)(aqh + rf * 4096 + kc * 512);
            al[rf] = *(const bf16x8*)(aql + rf * 4096 + kc * 512);
        }
        bf16x8 bh[4], bl[4];
#pragma unroll
        for (int cg = 0; cg < 4; ++cg) {
            int n = 16 * cg + m;
            int off = (n * 512 + (32 * kc + 8 * g) * 2) ^ ((n & 31) << 4);
            bh[cg] = *(const bf16x8*)(L0 + off);
            bl[cg] = *(const bf16x8*)(L1 + off);
        }
        __builtin_amdgcn_s_setprio(1);
#pragma unroll
        for (int rf = 0; rf < 2; ++rf)
#pragma unroll
            for (int cg = 0; cg < 4; ++cg) {
                qacc[rf][cg] = MFMA16(ah[rf], bh[cg], qacc[rf][cg]);
                qacc[rf][cg] = MFMA16(ah[rf], bl[cg], qacc[rf][cg]);
                qacc[rf][cg] = MFMA16(al[rf], bh[cg], qacc[rf][cg]);
            }
        __builtin_amdgcn_s_setprio(0);
    }

    // ---- softmax over d (in-register; head = w) ----
    float zinv[4];
#pragma unroll
    for (int cg = 0; cg < 4; ++cg) {
        float s = 0.f;
#pragma unroll
        for (int rf = 0; rf < 2; ++rf)
#pragma unroll
            for (int r = 0; r < 4; ++r) {
                float e = __expf(qacc[rf][cg][r]);
                qacc[rf][cg][r] = e;
                s += e;
            }
        s += __shfl_xor(s, 16);
        s += __shfl_xor(s, 32);
        zinv[cg] = 1.f / s;   // SCALE folded into M
    }

    __syncthreads();

    // ---- write QsmT[n][hd] bf16 hi/lo (aliased over XT planes) ----
#pragma unroll
    for (int rf = 0; rf < 2; ++rf)
#pragma unroll
        for (int cg = 0; cg < 4; ++cg) {
            int n = 16 * cg + m;
            int hd0 = 32 * w + 16 * rf + 4 * g;
            u16x4 vh, vl;
#pragma unroll
            for (int r = 0; r < 4; ++r) {
                float qv = qacc[rf][cg][r] * zinv[cg];
                unsigned short hv = f2bf(qv);
                vh[r] = hv;
                vl[r] = f2bf(qv - bf2f(hv));
            }
            int off = (n * 512 + hd0 * 2) ^ ((n & 31) << 4);
            *(u16x4*)(L0 + off) = vh;
            *(u16x4*)(L1 + off) = vl;
        }
    __syncthreads();

    // ---- GEMM2: oacc[rf][cg] = OUT[32w+16rf+4g+r][n0+16cg+m], split-bf16 ----
    f32x4 oacc[2][4];
#pragma unroll
    for (int rf = 0; rf < 2; ++rf)
#pragma unroll
        for (int cg = 0; cg < 4; ++cg) oacc[rf][cg] = (f32x4)0.f;

    const unsigned short* Mh = mfhi + (size_t)bf * 65536 + w * 8192 + l * 8;
    const unsigned short* Ml = mflo + (size_t)bf * 65536 + w * 8192 + l * 8;
    for (int kc = 0; kc < 8; ++kc) {
        bf16x8 ah[2], al[2];
#pragma unroll
        for (int rf = 0; rf < 2; ++rf) {
            ah[rf] = *(const bf16x8*)(Mh + rf * 4096 + kc * 512);
            al[rf] = *(const bf16x8*)(Ml + rf * 4096 + kc * 512);
        }
        bf16x8 bh[4], bl[4];
#pragma unroll
        for (int cg = 0; cg < 4; ++cg) {
            int n = 16 * cg + m;
            int off = (n * 512 + (32 * kc + 8 * g) * 2) ^ ((n & 31) << 4);
            bh[cg] = *(const bf16x8*)(L0 + off);
            bl[cg] = *(const bf16x8*)(L1 + off);
        }
        __builtin_amdgcn_s_setprio(1);
#pragma unroll
        for (int rf = 0; rf < 2; ++rf)
#pragma unroll
            for (int cg = 0; cg < 4; ++cg) {
                oacc[rf][cg] = MFMA16(ah[rf], bh[cg], oacc[rf][cg]);
                oacc[rf][cg] = MFMA16(ah[rf], bl[cg], oacc[rf][cg]);
                oacc[rf][cg] = MFMA16(al[rf], bh[cg], oacc[rf][cg]);
            }
        __builtin_amdgcn_s_setprio(0);
    }

    // ---- epilogue: + bias, nt stores ----
#pragma unroll
    for (int rf = 0; rf < 2; ++rf) {
        float bb[4];
#pragma unroll
        for (int r = 0; r < 4; ++r) bb[r] = bout[32 * w + 16 * rf + 4 * g + r];
#pragma unroll
        for (int cg = 0; cg < 4; ++cg) {
            int n = n0 + 16 * cg + m;
#pragma unroll
            for (int r = 0; r < 4; ++r) {
                int o = 32 * w + 16 * rf + 4 * g + r;
                __builtin_nontemporal_store(oacc[rf][cg][r] + bb[r], &og[(size_t)o * FN + n]);
            }
        }
    }
}

extern "C" void kernel_launch(void* const* d_in, const int* in_sizes, int n_in,
                              void* d_out, int out_size, void* d_ws, size_t ws_size,
                              hipStream_t stream) {
    const float* x    = (const float*)d_in[0];
    const float* wqkv = (const float*)d_in[1];
    const float* wout = (const float*)d_in[2];
    const float* bout = (const float*)d_in[3];
    float* out = (float*)d_out;
    float* ws  = (float*)d_ws;

    size_t partc_elems = (size_t)BF * NS * 256 * 32;
    size_t partz_elems = (size_t)BF * NS * 256;
    float* partC = ws;
    float* partz = ws + partc_elems;
    unsigned short* U = (unsigned short*)(ws + partc_elems + partz_elems);
    unsigned short* wqfhi  = U + WQHI_O;
    unsigned short* wqflo  = U + WQLO_O;
    unsigned short* wkvfhi = U + WKVHI_O;
    unsigned short* wkvflo = U + WKVLO_O;
    unsigned short* Mfhi   = U + MHI_O;
    unsigned short* Mflo   = U + MLO_O;

    k0_prep<<<768, 256, 0, stream>>>(wqkv, wqfhi, wqflo, wkvfhi, wkvflo);
    k1_mfma<<<dim3(NS, BF), 512, 0, stream>>>(x, wkvfhi, wkvflo, partC, partz);
    k2_M<<<dim3(BF, HEADS), 256, 0, stream>>>(partC, partz, wout, Mfhi, Mflo, NS);
    k3_mfma<<<dim3(NN / TN3, BF), 512, 0, stream>>>(x, wqfhi, wqflo, Mfhi, Mflo, bout, out);
}